// Round 2
// baseline (1076.201 us; speedup 1.0000x reference)
//
#include <hip/hip_runtime.h>

#define DIM   128
#define MSZ   (DIM*DIM)      // 16384 elements per matrix

// ============================ f64 expm stage ============================
// dbuf slots (each slot = 2 prims x 16384 doubles):
// 0:Hs  1:H2  2:H3  3:H4  4:H5  5:Q0  6:R  7:E
// V_b = prim_b^T = expm((P_b - P_b^T)^T) = expm(P_b^T - P_b), so build the
// transposed herm directly and never transpose again. Scale by 2^-8 so
// ||Hs||_1 <= 0.5 -> degree-10 Taylor error ~1e-11, then 8 squarings.

__global__ __launch_bounds__(256) void k_herm(const float* __restrict__ P,
                                              double* __restrict__ dbuf) {
  const int b = blockIdx.y;
  const float* Pb = P + b * MSZ;
  double* H = dbuf + (size_t)(0*2 + b) * MSZ;
  for (int idx = blockIdx.x*256 + threadIdx.x; idx < MSZ; idx += 32*256) {
    const int x = idx >> 7, y = idx & 127;
    H[idx] = ((double)Pb[y*DIM + x] - (double)Pb[x*DIM + y]) * (1.0/256.0);
  }
}

// C = A*B (+ Add), all 128x128 f64, slot-indexed. grid (64, 2), 256 thr.
__global__ __launch_bounds__(256) void k_mm64(double* __restrict__ dbuf,
                                              int ds, int as, int bs, int adds) {
  const int b = blockIdx.y;
  const double* A = dbuf + (size_t)(as*2 + b) * MSZ;
  const double* B = dbuf + (size_t)(bs*2 + b) * MSZ;
  double*       C = dbuf + (size_t)(ds*2 + b) * MSZ;
  const int idx = blockIdx.x*256 + threadIdx.x;   // 16384 threads per prim
  const int i = idx >> 7, j = idx & 127;
  const double* Ar = A + i*DIM;
  double a0 = 0.0, a1 = 0.0, a2 = 0.0, a3 = 0.0;
  #pragma unroll 4
  for (int k = 0; k < DIM; k += 4) {
    a0 = fma(Ar[k+0], B[(k+0)*DIM + j], a0);
    a1 = fma(Ar[k+1], B[(k+1)*DIM + j], a1);
    a2 = fma(Ar[k+2], B[(k+2)*DIM + j], a2);
    a3 = fma(Ar[k+3], B[(k+3)*DIM + j], a3);
  }
  double acc = (a0 + a1) + (a2 + a3);
  if (adds >= 0) acc += (dbuf + (size_t)(adds*2 + b)*MSZ)[idx];
  C[idx] = acc;
}

// Q0 = I + H + H2/2 + H3/6 + H4/24 ;  R = I/120 + ... + H5/10! (Paterson-Stockmeyer)
__global__ __launch_bounds__(256) void k_qelem(double* __restrict__ dbuf) {
  const int b = blockIdx.y;
  const double *H  = dbuf + (size_t)(0*2+b)*MSZ, *H2 = dbuf + (size_t)(1*2+b)*MSZ,
               *H3 = dbuf + (size_t)(2*2+b)*MSZ, *H4 = dbuf + (size_t)(3*2+b)*MSZ,
               *H5 = dbuf + (size_t)(4*2+b)*MSZ;
  double *Q0 = dbuf + (size_t)(5*2+b)*MSZ, *R = dbuf + (size_t)(6*2+b)*MSZ;
  for (int idx = blockIdx.x*256 + threadIdx.x; idx < MSZ; idx += 32*256) {
    const double di = ((idx >> 7) == (idx & 127)) ? 1.0 : 0.0;
    const double h = H[idx], h2 = H2[idx], h3 = H3[idx], h4 = H4[idx], h5 = H5[idx];
    Q0[idx] = di + h + h2*(1.0/2.0) + h3*(1.0/6.0) + h4*(1.0/24.0);
    R[idx]  = di*(1.0/120.0) + h*(1.0/720.0) + h2*(1.0/5040.0)
            + h3*(1.0/40320.0) + h4*(1.0/362880.0) + h5*(1.0/3628800.0);
  }
}

// T table lives in ws as fp32, heap-indexed: T[p] = product of V over bits of
// p below its leading 1 (LSB factor leftmost).  T[1]=I, T[2]=V0, T[3]=V1,
// T[2^k + m] = F_k[m], up to F8 (full 8-bit products) at T[256..511].
// 511 live matrices * 64 KiB -> table occupies 32 MiB of ws.
__global__ __launch_bounds__(256) void k_finalize(const double* __restrict__ dbuf,
                                                  float* __restrict__ T) {
  const int role = blockIdx.y;            // 0,1: cast E_b -> T[2+b];  2: T[1]=I
  if (role == 2) {
    for (int idx = blockIdx.x*256 + threadIdx.x; idx < MSZ; idx += 32*256)
      T[(size_t)1*MSZ + idx] = ((idx >> 7) == (idx & 127)) ? 1.0f : 0.0f;
  } else {
    const double* E = dbuf + (size_t)(7*2 + role)*MSZ;
    float* dst = T + (size_t)(2 + role)*MSZ;
    for (int idx = blockIdx.x*256 + threadIdx.x; idx < MSZ; idx += 32*256)
      dst[idx] = (float)E[idx];
  }
}

// ======================= fp32 128x128 block matmul =======================
// One workgroup (256 thr) computes C = A*B.  B staged in LDS (64 KiB),
// A streamed from global (16x intra-block reuse -> L1/L2 hits).  8x8
// register tile per thread, 64 fp32 FMA per k-step per thread -> VALU-bound.
__device__ __forceinline__ void mm128f(const float* __restrict__ A,
                                       const float* __restrict__ Bg,
                                       float* __restrict__ C) {
  __shared__ float Bs[MSZ];                       // 64 KiB -> 2 blocks/CU
  for (int idx = threadIdx.x*4; idx < MSZ; idx += 256*4)
    *(float4*)&Bs[idx] = *(const float4*)&Bg[idx];
  __syncthreads();

  const int t  = threadIdx.x;
  const int i0 = (t >> 4) << 3;
  const int j0 = (t & 15) << 3;

  float acc[8][8];
  #pragma unroll
  for (int r = 0; r < 8; ++r)
    #pragma unroll
    for (int c = 0; c < 8; ++c) acc[r][c] = 0.0f;

  for (int k = 0; k < DIM; k += 4) {
    alignas(16) float aa[8][4];
    #pragma unroll
    for (int r = 0; r < 8; ++r)
      *(float4*)&aa[r][0] = *(const float4*)&A[(i0 + r)*DIM + k];
    #pragma unroll
    for (int kk = 0; kk < 4; ++kk) {
      alignas(16) float bb[8];
      *(float4*)&bb[0] = *(const float4*)&Bs[(k + kk)*DIM + j0];
      *(float4*)&bb[4] = *(const float4*)&Bs[(k + kk)*DIM + j0 + 4];
      #pragma unroll
      for (int r = 0; r < 8; ++r) {
        const float ar = aa[r][kk];
        #pragma unroll
        for (int c = 0; c < 8; ++c) acc[r][c] = fmaf(ar, bb[c], acc[r][c]);
      }
    }
  }

  #pragma unroll
  for (int r = 0; r < 8; ++r) {
    *(float4*)&C[(i0 + r)*DIM + j0]
        = make_float4(acc[r][0], acc[r][1], acc[r][2], acc[r][3]);
    *(float4*)&C[(i0 + r)*DIM + j0 + 4]
        = make_float4(acc[r][4], acc[r][5], acc[r][6], acc[r][7]);
  }
}

// Table build by doubling: F_{a+b}[m] = F_a[m & (2^a-1)] * F_b[m >> a].
// wave 0: F2 (4 jobs); wave 1: F3,F4 (24); wave 2: F5..F8 (480).
__global__ __launch_bounds__(256) void k_jobs(float* __restrict__ T, int wave) {
  const int j = blockIdx.x;
  int dst, a, b;
  if (wave == 0)      { dst = 4 + j;   a = 2 + (j & 1);  b = 2 + (j >> 1); }
  else if (wave == 1) {
    if (j < 8)        { dst = 8 + j;   a = 2 + (j & 1);  b = 4 + (j >> 1); }
    else { const int m = j - 8;   dst = 16 + m;  a = 4 + (m & 3);  b = 4 + (m >> 2); }
  } else {
    if (j < 32)       { const int m = j;       dst = 32 + m;  a = 2 + (m & 1);  b = 16 + (m >> 1); }
    else if (j < 96)  { const int m = j - 32;  dst = 64 + m;  a = 4 + (m & 3);  b = 16 + (m >> 2); }
    else if (j < 224) { const int m = j - 96;  dst = 128 + m; a = 8 + (m & 7);  b = 16 + (m >> 3); }
    else              { const int m = j - 224; dst = 256 + m; a = 16 + (m & 15); b = 16 + (m >> 4); }
  }
  mm128f(T + (size_t)a*MSZ, T + (size_t)b*MSZ, T + (size_t)dst*MSZ);
}

// out(pos) = T[pos<256 ? pos : 256|(pos&255)] * T[max(pos>>8,1)]
__global__ __launch_bounds__(256) void k_final(const float* __restrict__ T,
                                               const int* __restrict__ unique,
                                               float* __restrict__ out) {
  const int n   = blockIdx.x;
  int pos = unique[n];
  pos = (pos < 1) ? 1 : (pos & 0xFFFF);       // defensive clamp: table is [1,511]-indexed below
  const int hi  = pos >> 8;
  const int ai  = (hi == 0) ? pos : (256 | (pos & 255));
  const int bi  = (hi == 0) ? 1 : hi;
  mm128f(T + (size_t)ai*MSZ, T + (size_t)bi*MSZ, out + (size_t)n*MSZ);
}

// ================================ launch ================================
extern "C" void kernel_launch(void* const* d_in, const int* in_sizes, int n_in,
                              void* d_out, int out_size, void* d_ws, size_t ws_size,
                              hipStream_t stream) {
  const int*   unique = (const int*)d_in[0];
  const float* praw   = (const float*)d_in[1];
  // d_in[2] (identity) unused.
  const int n = in_sizes[0];                          // 8192 positions
  double* dbuf = (double*)d_ws;                       // 8 slots * 2 * 128KiB = 2 MiB
  float*  T    = (float*)((char*)d_ws + (4u << 20));  // 32 MiB table @ +4 MiB
  float*  out  = (float*)d_out;

  // ---- expm (f64, safe) ----
  k_herm <<<dim3(32,2),256,0,stream>>>(praw, dbuf);
  k_mm64 <<<dim3(64,2),256,0,stream>>>(dbuf, 1,0,0, -1);   // H2 = Hs*Hs
  k_mm64 <<<dim3(64,2),256,0,stream>>>(dbuf, 2,1,0, -1);   // H3 = H2*Hs
  k_mm64 <<<dim3(64,2),256,0,stream>>>(dbuf, 3,1,1, -1);   // H4 = H2*H2
  k_mm64 <<<dim3(64,2),256,0,stream>>>(dbuf, 4,1,2, -1);   // H5 = H2*H3
  k_qelem<<<dim3(32,2),256,0,stream>>>(dbuf);
  k_mm64 <<<dim3(64,2),256,0,stream>>>(dbuf, 7,6,4, 5);    // E = R*H5 + Q0
  int cur = 7;
  for (int s = 0; s < 8; ++s) {                            // 8 squarings
    const int nxt = cur ^ 1;
    k_mm64<<<dim3(64,2),256,0,stream>>>(dbuf, nxt, cur, cur, -1);
    cur = nxt;
  }                                                        // ends in slot 7
  k_finalize<<<dim3(32,3),256,0,stream>>>(dbuf, T);        // T[1]=I, T[2]=V0, T[3]=V1

  // ---- table build: 3 doubling waves ----
  k_jobs<<<dim3(4),  256,0,stream>>>(T, 0);
  k_jobs<<<dim3(24), 256,0,stream>>>(T, 1);
  k_jobs<<<dim3(480),256,0,stream>>>(T, 2);

  // ---- one matmul per position ----
  k_final<<<dim3(n),256,0,stream>>>(T, unique, out);
}

// Round 3
// 1000.930 us; speedup vs baseline: 1.0752x; 1.0752x over previous
//
#include <hip/hip_runtime.h>
#include <hip/hip_bf16.h>

#define DIM   128
#define MSZ   (DIM*DIM)      // 16384 elements per matrix

typedef __attribute__((ext_vector_type(8))) short          v8s;    // 8 bf16 (4 VGPR) MFMA frag
typedef __attribute__((ext_vector_type(4))) float          f32x4;  // MFMA 16x16 accum
typedef __attribute__((ext_vector_type(8))) unsigned short u16x8;  // 16B staging chunk

// ============================ f64 expm stage ============================
// dbuf slots (each slot = 2 prims x 16384 doubles):
// 0:Hs  1:H2  2:H3  3:H4  4:H5  5:Q0  6:R  7:E
// V_b = expm(P_b^T - P_b) (transposed herm built directly; no transposes later).
// Scale 2^-8 -> ||Hs||_1 <= 127/256 < 0.5, deg-10 Taylor ~1e-11, 8 squarings.

__global__ __launch_bounds__(256) void k_herm(const float* __restrict__ P,
                                              double* __restrict__ dbuf) {
  const int b = blockIdx.y;
  const float* Pb = P + b * MSZ;
  double* H = dbuf + (size_t)(0*2 + b) * MSZ;
  for (int idx = blockIdx.x*256 + threadIdx.x; idx < MSZ; idx += 32*256) {
    const int x = idx >> 7, y = idx & 127;
    H[idx] = ((double)Pb[y*DIM + x] - (double)Pb[x*DIM + y]) * (1.0/256.0);
  }
}

__global__ __launch_bounds__(256) void k_mm64(double* __restrict__ dbuf,
                                              int ds, int as, int bs, int adds) {
  const int b = blockIdx.y;
  const double* A = dbuf + (size_t)(as*2 + b) * MSZ;
  const double* B = dbuf + (size_t)(bs*2 + b) * MSZ;
  double*       C = dbuf + (size_t)(ds*2 + b) * MSZ;
  const int idx = blockIdx.x*256 + threadIdx.x;
  const int i = idx >> 7, j = idx & 127;
  const double* Ar = A + i*DIM;
  double a0 = 0.0, a1 = 0.0, a2 = 0.0, a3 = 0.0;
  #pragma unroll 4
  for (int k = 0; k < DIM; k += 4) {
    a0 = fma(Ar[k+0], B[(k+0)*DIM + j], a0);
    a1 = fma(Ar[k+1], B[(k+1)*DIM + j], a1);
    a2 = fma(Ar[k+2], B[(k+2)*DIM + j], a2);
    a3 = fma(Ar[k+3], B[(k+3)*DIM + j], a3);
  }
  double acc = (a0 + a1) + (a2 + a3);
  if (adds >= 0) acc += (dbuf + (size_t)(adds*2 + b)*MSZ)[idx];
  C[idx] = acc;
}

__global__ __launch_bounds__(256) void k_qelem(double* __restrict__ dbuf) {
  const int b = blockIdx.y;
  const double *H  = dbuf + (size_t)(0*2+b)*MSZ, *H2 = dbuf + (size_t)(1*2+b)*MSZ,
               *H3 = dbuf + (size_t)(2*2+b)*MSZ, *H4 = dbuf + (size_t)(3*2+b)*MSZ,
               *H5 = dbuf + (size_t)(4*2+b)*MSZ;
  double *Q0 = dbuf + (size_t)(5*2+b)*MSZ, *R = dbuf + (size_t)(6*2+b)*MSZ;
  for (int idx = blockIdx.x*256 + threadIdx.x; idx < MSZ; idx += 32*256) {
    const double di = ((idx >> 7) == (idx & 127)) ? 1.0 : 0.0;
    const double h = H[idx], h2 = H2[idx], h3 = H3[idx], h4 = H4[idx], h5 = H5[idx];
    Q0[idx] = di + h + h2*(1.0/2.0) + h3*(1.0/6.0) + h4*(1.0/24.0);
    R[idx]  = di*(1.0/120.0) + h*(1.0/720.0) + h2*(1.0/5040.0)
            + h3*(1.0/40320.0) + h4*(1.0/362880.0) + h5*(1.0/3628800.0);
  }
}

// ======================= bf16x3 split helpers =======================
__device__ __forceinline__ unsigned short bf16_bits(float f) {
  union { __hip_bfloat16 b; unsigned short u; } cv;
  cv.b = __float2bfloat16(f);
  return cv.u;
}
__device__ __forceinline__ float bf16_back(unsigned short u) {
  union { __hip_bfloat16 b; unsigned short u; } cv;
  cv.u = u;
  return __bfloat162float(cv.b);
}
__device__ __forceinline__ void split3(float x, unsigned short& u0,
                                       unsigned short& u1, unsigned short& u2) {
  u0 = bf16_bits(x);              float f0 = bf16_back(u0);
  u1 = bf16_bits(x - f0);         float f1 = bf16_back(u1);
  u2 = bf16_bits(x - f0 - f1);
}

// Table layout in ws (MFMA path):
//   T3  : ushort [3 comp][512 entries][16384]  (row-major matrices, A-operands)
//   T3T : ushort [3 comp][256 entries][16384]  (transposed matrices, B-operands)
// Heap index: T[p] = product of V over bits of p below leading 1 (LSB leftmost).
#define T3_ENT  512
#define T3T_ENT 256

// entries 1 (I), 2 (V0), 3 (V1) from the f64 E, split into both layouts
__global__ __launch_bounds__(256) void k_finalize_splits(const double* __restrict__ dbuf,
                                                         unsigned short* __restrict__ T3,
                                                         unsigned short* __restrict__ T3T) {
  const int role = blockIdx.y;            // 0,1 -> V0,V1 (entries 2,3); 2 -> I (entry 1)
  const int ent  = (role == 2) ? 1 : (2 + role);
  const double* E = dbuf + (size_t)(7*2 + (role & 1)) * MSZ;
  for (int idx = blockIdx.x*256 + threadIdx.x; idx < MSZ; idx += 32*256) {
    const int row = idx >> 7, col = idx & 127;
    const float x = (role == 2) ? ((row == col) ? 1.0f : 0.0f) : (float)E[idx];
    unsigned short u0, u1, u2;
    split3(x, u0, u1, u2);
    const size_t e3  = (size_t)ent * MSZ + idx;
    const size_t e3t = (size_t)ent * MSZ + col*DIM + row;
    T3 [(size_t)0*T3_ENT*MSZ  + e3 ] = u0;
    T3 [(size_t)1*T3_ENT*MSZ  + e3 ] = u1;
    T3 [(size_t)2*T3_ENT*MSZ  + e3 ] = u2;
    T3T[(size_t)0*T3T_ENT*MSZ + e3t] = u0;
    T3T[(size_t)1*T3T_ENT*MSZ + e3t] = u1;
    T3T[(size_t)2*T3T_ENT*MSZ + e3t] = u2;
  }
}

// ================= MFMA 128x128 matmul core (bf16x3, 6 products) =================
// C = T[ea] * T[eb].  A-frags from T3 (row-major), B-frags via LDS-staged T3T
// (col-major of B) with (col&15)<<4 XOR swizzle -> conflict-free ds_read_b128.
// 256 thr = 4 waves; wave w owns rows [w*32, w*32+32) as 2x8 tiles of 16x16.
__device__ __forceinline__ void mm_mfma_core(const unsigned short* __restrict__ T3,
                                             const unsigned short* __restrict__ T3T,
                                             int ea, int eb,
                                             unsigned short* __restrict__ smem,
                                             f32x4 (&acc)[2][8]) {
  const int t   = threadIdx.x;
  const int w   = t >> 6;
  const int l   = t & 63;
  const int l15 = l & 15;
  const int g   = l >> 4;          // k-group (4 groups of 8 k each)

  #pragma unroll
  for (int tr = 0; tr < 2; ++tr)
    #pragma unroll
    for (int tc = 0; tc < 8; ++tc) acc[tr][tc] = (f32x4)(0.0f);

  #pragma unroll
  for (int q = 0; q < 3; ++q) {    // B split-component (phase)
    // ---- stage B_q (transposed layout) into LDS, swizzled ----
    const unsigned short* src = T3T + ((size_t)q * T3T_ENT + eb) * MSZ;
    #pragma unroll
    for (int it = 0; it < 8; ++it) {
      const int e   = (it*256 + t) * 8;        // element index (8 bf16 per chunk)
      const int col = e >> 7;
      int off = col*256 + (e & 127)*2;         // byte offset, row-major [col][k]
      off ^= (col & 15) << 4;                  // XOR swizzle (bank-conflict-free)
      *(u16x8*)((char*)smem + off) = *(const u16x8*)(src + e);
    }
    __syncthreads();

    #pragma unroll
    for (int ks = 0; ks < 4; ++ks) {           // K-step of 32
      v8s bf[8];
      #pragma unroll
      for (int tc = 0; tc < 8; ++tc) {         // B-frag: col = tc*16+l15, k = ks*32+g*8..+8
        const int col = tc*16 + l15;
        int off = col*256 + ks*64 + g*16;
        off ^= (col & 15) << 4;
        bf[tc] = *(const v8s*)((const char*)smem + off);
      }
      v8s af[3][2];
      #pragma unroll
      for (int p = 0; p < 3 - q; ++p) {        // A split-component
        const unsigned short* ap = T3 + ((size_t)p * T3_ENT + ea) * MSZ;
        #pragma unroll
        for (int tr = 0; tr < 2; ++tr) {
          const int row = w*32 + tr*16 + l15;
          af[p][tr] = *(const v8s*)(ap + row*DIM + ks*32 + g*8);
        }
      }
      #pragma unroll
      for (int p = 0; p < 3 - q; ++p)
        #pragma unroll
        for (int tr = 0; tr < 2; ++tr)
          #pragma unroll
          for (int tc = 0; tc < 8; ++tc)
            acc[tr][tc] = __builtin_amdgcn_mfma_f32_16x16x32_bf16(
                              af[p][tr], bf[tc], acc[tr][tc], 0, 0, 0);
    }
    __syncthreads();
  }
}

// Table build by doubling: F_{a+b}[m] = F_a[m & (2^a-1)] * F_b[m >> a].
__global__ __launch_bounds__(256, 2) void k_jobs_mfma(unsigned short* __restrict__ T3,
                                                      unsigned short* __restrict__ T3T,
                                                      int wave) {
  const int j = blockIdx.x;
  int dst, a, b;
  if (wave == 0)      { dst = 4 + j;   a = 2 + (j & 1);  b = 2 + (j >> 1); }
  else if (wave == 1) {
    if (j < 8)        { dst = 8 + j;   a = 2 + (j & 1);  b = 4 + (j >> 1); }
    else { const int m = j - 8;   dst = 16 + m;  a = 4 + (m & 3);  b = 4 + (m >> 2); }
  } else {
    if (j < 32)       { const int m = j;       dst = 32 + m;  a = 2 + (m & 1);  b = 16 + (m >> 1); }
    else if (j < 96)  { const int m = j - 32;  dst = 64 + m;  a = 4 + (m & 3);  b = 16 + (m >> 2); }
    else if (j < 224) { const int m = j - 96;  dst = 128 + m; a = 8 + (m & 7);  b = 16 + (m >> 3); }
    else              { const int m = j - 224; dst = 256 + m; a = 16 + (m & 15); b = 16 + (m >> 4); }
  }
  __shared__ unsigned short smem[MSZ];
  f32x4 acc[2][8];
  mm_mfma_core(T3, T3T, a, b, smem, acc);

  const int t = threadIdx.x, w = t >> 6, l = t & 63, l15 = l & 15, g = l >> 4;
  #pragma unroll
  for (int tr = 0; tr < 2; ++tr)
    #pragma unroll
    for (int tc = 0; tc < 8; ++tc)
      #pragma unroll
      for (int r = 0; r < 4; ++r) {
        const int row = w*32 + tr*16 + g*4 + r;   // C/D: row=(lane>>4)*4+reg
        const int col = tc*16 + l15;              //      col=lane&15
        unsigned short u0, u1, u2;
        split3(acc[tr][tc][r], u0, u1, u2);
        const size_t e3 = (size_t)dst * MSZ + row*DIM + col;
        T3[(size_t)0*T3_ENT*MSZ + e3] = u0;
        T3[(size_t)1*T3_ENT*MSZ + e3] = u1;
        T3[(size_t)2*T3_ENT*MSZ + e3] = u2;
        if (dst < T3T_ENT) {                      // only entries used as B-operands
          const size_t e3t = (size_t)dst * MSZ + col*DIM + row;
          T3T[(size_t)0*T3T_ENT*MSZ + e3t] = u0;
          T3T[(size_t)1*T3T_ENT*MSZ + e3t] = u1;
          T3T[(size_t)2*T3T_ENT*MSZ + e3t] = u2;
        }
      }
}

// out(pos) = T[pos<256 ? pos : 256|(pos&255)] * T[max(pos>>8,1)]
__global__ __launch_bounds__(256, 2) void k_final_mfma(const unsigned short* __restrict__ T3,
                                                       const unsigned short* __restrict__ T3T,
                                                       const int* __restrict__ unique,
                                                       float* __restrict__ out) {
  const int n = blockIdx.x;
  int pos = unique[n];
  pos = (pos < 1) ? 1 : (pos & 0xFFFF);
  const int hi = pos >> 8;
  const int ea = hi ? (256 | (pos & 255)) : pos;
  const int eb = hi ? hi : 1;

  __shared__ unsigned short smem[MSZ];
  f32x4 acc[2][8];
  mm_mfma_core(T3, T3T, ea, eb, smem, acc);

  const int t = threadIdx.x, w = t >> 6, l = t & 63, l15 = l & 15, g = l >> 4;
  float* o = out + (size_t)n * MSZ;
  #pragma unroll
  for (int tr = 0; tr < 2; ++tr)
    #pragma unroll
    for (int tc = 0; tc < 8; ++tc)
      #pragma unroll
      for (int r = 0; r < 4; ++r) {
        const int row = w*32 + tr*16 + g*4 + r;
        const int col = tc*16 + l15;
        o[row*DIM + col] = acc[tr][tc][r];
      }
}

// =================== fallback fp32 path (round-2, proven) ===================
__global__ __launch_bounds__(256) void k_finalize(const double* __restrict__ dbuf,
                                                  float* __restrict__ T) {
  const int role = blockIdx.y;
  if (role == 2) {
    for (int idx = blockIdx.x*256 + threadIdx.x; idx < MSZ; idx += 32*256)
      T[(size_t)1*MSZ + idx] = ((idx >> 7) == (idx & 127)) ? 1.0f : 0.0f;
  } else {
    const double* E = dbuf + (size_t)(7*2 + role)*MSZ;
    float* dst = T + (size_t)(2 + role)*MSZ;
    for (int idx = blockIdx.x*256 + threadIdx.x; idx < MSZ; idx += 32*256)
      dst[idx] = (float)E[idx];
  }
}

__device__ __forceinline__ void mm128f(const float* __restrict__ A,
                                       const float* __restrict__ Bg,
                                       float* __restrict__ C) {
  __shared__ float Bs[MSZ];
  for (int idx = threadIdx.x*4; idx < MSZ; idx += 256*4)
    *(float4*)&Bs[idx] = *(const float4*)&Bg[idx];
  __syncthreads();
  const int t  = threadIdx.x;
  const int i0 = (t >> 4) << 3;
  const int j0 = (t & 15) << 3;
  float acc[8][8];
  #pragma unroll
  for (int r = 0; r < 8; ++r)
    #pragma unroll
    for (int c = 0; c < 8; ++c) acc[r][c] = 0.0f;
  for (int k = 0; k < DIM; k += 4) {
    alignas(16) float aa[8][4];
    #pragma unroll
    for (int r = 0; r < 8; ++r)
      *(float4*)&aa[r][0] = *(const float4*)&A[(i0 + r)*DIM + k];
    #pragma unroll
    for (int kk = 0; kk < 4; ++kk) {
      alignas(16) float bb[8];
      *(float4*)&bb[0] = *(const float4*)&Bs[(k + kk)*DIM + j0];
      *(float4*)&bb[4] = *(const float4*)&Bs[(k + kk)*DIM + j0 + 4];
      #pragma unroll
      for (int r = 0; r < 8; ++r) {
        const float ar = aa[r][kk];
        #pragma unroll
        for (int c = 0; c < 8; ++c) acc[r][c] = fmaf(ar, bb[c], acc[r][c]);
      }
    }
  }
  #pragma unroll
  for (int r = 0; r < 8; ++r) {
    *(float4*)&C[(i0 + r)*DIM + j0]
        = make_float4(acc[r][0], acc[r][1], acc[r][2], acc[r][3]);
    *(float4*)&C[(i0 + r)*DIM + j0 + 4]
        = make_float4(acc[r][4], acc[r][5], acc[r][6], acc[r][7]);
  }
}

__global__ __launch_bounds__(256) void k_jobs(float* __restrict__ T, int wave) {
  const int j = blockIdx.x;
  int dst, a, b;
  if (wave == 0)      { dst = 4 + j;   a = 2 + (j & 1);  b = 2 + (j >> 1); }
  else if (wave == 1) {
    if (j < 8)        { dst = 8 + j;   a = 2 + (j & 1);  b = 4 + (j >> 1); }
    else { const int m = j - 8;   dst = 16 + m;  a = 4 + (m & 3);  b = 4 + (m >> 2); }
  } else {
    if (j < 32)       { const int m = j;       dst = 32 + m;  a = 2 + (m & 1);  b = 16 + (m >> 1); }
    else if (j < 96)  { const int m = j - 32;  dst = 64 + m;  a = 4 + (m & 3);  b = 16 + (m >> 2); }
    else if (j < 224) { const int m = j - 96;  dst = 128 + m; a = 8 + (m & 7);  b = 16 + (m >> 3); }
    else              { const int m = j - 224; dst = 256 + m; a = 16 + (m & 15); b = 16 + (m >> 4); }
  }
  mm128f(T + (size_t)a*MSZ, T + (size_t)b*MSZ, T + (size_t)dst*MSZ);
}

__global__ __launch_bounds__(256) void k_final(const float* __restrict__ T,
                                               const int* __restrict__ unique,
                                               float* __restrict__ out) {
  const int n   = blockIdx.x;
  int pos = unique[n];
  pos = (pos < 1) ? 1 : (pos & 0xFFFF);
  const int hi  = pos >> 8;
  const int ai  = (hi == 0) ? pos : (256 | (pos & 255));
  const int bi  = (hi == 0) ? 1 : hi;
  mm128f(T + (size_t)ai*MSZ, T + (size_t)bi*MSZ, out + (size_t)n*MSZ);
}

// ================================ launch ================================
extern "C" void kernel_launch(void* const* d_in, const int* in_sizes, int n_in,
                              void* d_out, int out_size, void* d_ws, size_t ws_size,
                              hipStream_t stream) {
  const int*   unique = (const int*)d_in[0];
  const float* praw   = (const float*)d_in[1];
  const int n = in_sizes[0];
  double* dbuf = (double*)d_ws;                       // 2 MiB @ 0
  float*  out  = (float*)d_out;

  // ---- expm (f64, shared by both paths) ----
  k_herm <<<dim3(32,2),256,0,stream>>>(praw, dbuf);
  k_mm64 <<<dim3(64,2),256,0,stream>>>(dbuf, 1,0,0, -1);   // H2 = Hs*Hs
  k_mm64 <<<dim3(64,2),256,0,stream>>>(dbuf, 2,1,0, -1);   // H3 = H2*Hs
  k_mm64 <<<dim3(64,2),256,0,stream>>>(dbuf, 3,1,1, -1);   // H4 = H2*H2
  k_mm64 <<<dim3(64,2),256,0,stream>>>(dbuf, 4,1,2, -1);   // H5 = H2*H3
  k_qelem<<<dim3(32,2),256,0,stream>>>(dbuf);
  k_mm64 <<<dim3(64,2),256,0,stream>>>(dbuf, 7,6,4, 5);    // E = R*H5 + Q0
  int cur = 7;
  for (int s = 0; s < 8; ++s) {                            // 8 squarings -> slot 7
    const int nxt = cur ^ 1;
    k_mm64<<<dim3(64,2),256,0,stream>>>(dbuf, nxt, cur, cur, -1);
    cur = nxt;
  }

  const size_t NEED = (size_t)76 << 20;   // T3 (48 MiB) + T3T (24 MiB) @ +4 MiB
  if (ws_size >= NEED) {
    // ---- MFMA bf16x3 path ----
    unsigned short* T3  = (unsigned short*)((char*)d_ws + ((size_t)4 << 20));
    unsigned short* T3T = T3 + (size_t)3 * T3_ENT * MSZ;

    k_finalize_splits<<<dim3(32,3),256,0,stream>>>(dbuf, T3, T3T);
    k_jobs_mfma<<<dim3(4),  256,0,stream>>>(T3, T3T, 0);
    k_jobs_mfma<<<dim3(24), 256,0,stream>>>(T3, T3T, 1);
    k_jobs_mfma<<<dim3(480),256,0,stream>>>(T3, T3T, 2);
    k_final_mfma<<<dim3(n),256,0,stream>>>(T3, T3T, unique, out);
  } else {
    // ---- fallback: proven fp32 path (needs 36 MiB) ----
    float* T = (float*)((char*)d_ws + ((size_t)4 << 20));
    k_finalize<<<dim3(32,3),256,0,stream>>>(dbuf, T);
    k_jobs<<<dim3(4),  256,0,stream>>>(T, 0);
    k_jobs<<<dim3(24), 256,0,stream>>>(T, 1);
    k_jobs<<<dim3(480),256,0,stream>>>(T, 2);
    k_final<<<dim3(n),256,0,stream>>>(T, unique, out);
  }
}